// Round 7
// baseline (83.837 us; speedup 1.0000x reference)
//
#include <hip/hip_runtime.h>
#include <hip/hip_bf16.h>

// Chamfer distance, B=16, N=M=4096, D=3, fp32 — MFMA 32x32x16, col-split.
//
// d2(s,t) = |s|^2+|t|^2-2 s.t via ONE K=16 bf16 mfma_f32_32x32x16 per 32x32
// tile with hi/lo bf16 splitting (slot layout verified absmax==0 R4/R5/R6):
//   A: [xh yh zh xh yh zh xl yl | zl fh fl 1 1 0 0 0]           (query s)
//   B: [-2xh -2yh -2zh -2xl -2yl -2zl -2xh -2yh | -2zh 1 1 fh fl 0 0 0] (t)
// Grid: dir(2) x batch(16) x strip(16 of 256 rows) x colhalf(2 of 2048 cols)
//     = 1024 blocks x 256 thr -> 4 blocks/CU, 16 waves/CU (latency hiding).
// Per block: 4 chunks of 512 cols, double-buffered LDS; next chunk's raw
// floats loaded into REGISTERS before the MFMA loop, converted + ds_write
// after it (vmcnt drain hidden under MFMA). Partial row-mins merged via
// 262k uint-bits atomicMin; final sum by the R1-proven reduce kernel.

#define BATCH   16
#define NPTS    4096
#define CHUNKC  512
#define COLSPB  2048                   // cols per block
#define NCHUNKS (COLSPB / CHUNKC)      // 4
#define NSTRIPS 16                     // 4096 / 256 rows per block
#define NMINS   (2 * BATCH * NPTS)     // 131072

typedef __attribute__((ext_vector_type(8)))  short short8;
typedef __attribute__((ext_vector_type(16))) float float16;

union U4S8 { uint4 u; short8 s; };

__device__ inline unsigned int bfb(float v) {
    __hip_bfloat16 h = __float2bfloat16(v);
    unsigned short u; __builtin_memcpy(&u, &h, 2);
    return (unsigned int)u;
}
__device__ inline float bff(float v) { return __bfloat162float(__float2bfloat16(v)); }

#define ONEB 0x3F80u

__device__ inline void buildA(float x, float y, float z, uint4& w0, uint4& w1) {
    float xhf = bff(x), yhf = bff(y), zhf = bff(z);
    float f = fmaf(x, x, fmaf(y, y, z * z));
    float fhf = bff(f);
    unsigned xh = bfb(xhf), yh = bfb(yhf), zh = bfb(zhf);
    unsigned xl = bfb(x - xhf), yl = bfb(y - yhf), zl = bfb(z - zhf);
    unsigned fh = bfb(fhf), fl = bfb(f - fhf);
    w0 = make_uint4(xh | (yh << 16), zh | (xh << 16),
                    yh | (zh << 16), xl | (yl << 16));
    w1 = make_uint4(zl | (fh << 16), fl | (ONEB << 16), ONEB, 0u);
}

__device__ inline void buildB(float x, float y, float z, uint4& w0, uint4& w1) {
    float xhf = bff(x), yhf = bff(y), zhf = bff(z);
    float f = fmaf(x, x, fmaf(y, y, z * z));
    float fhf = bff(f);
    unsigned a = bfb(-2.0f * xhf), b = bfb(-2.0f * yhf), c = bfb(-2.0f * zhf);
    unsigned d = bfb(-2.0f * (x - xhf)), e = bfb(-2.0f * (y - yhf)),
             g = bfb(-2.0f * (z - zhf));
    unsigned fh = bfb(fhf), fl = bfb(f - fhf);
    w0 = make_uint4(a | (b << 16), c | (d << 16),
                    e | (g << 16), a | (b << 16));
    w1 = make_uint4(c | (ONEB << 16), ONEB | (fh << 16), fl, 0u);
}

__global__ __launch_bounds__(256, 4) void chamfer_mfma_kernel(
    const float* __restrict__ src, const float* __restrict__ tgt,
    unsigned int* __restrict__ mins)
{
    __shared__ uint4 sbuf[2][2][CHUNKC];    // [buf][half][pt] = 32 KB

    int blk = blockIdx.x;
    const int ch    = blk & 1;             blk >>= 1;   // col half
    const int strip = blk & (NSTRIPS - 1); blk >>= 4;
    const int b     = blk & 15;            blk >>= 4;
    const int dir   = blk;

    const int lane = threadIdx.x & 63;
    const int w    = threadIdx.x >> 6;
    const int half = lane >> 5;
    const int l5   = lane & 31;

    const float* Araw = (dir ? tgt : src) + (size_t)b * NPTS * 3;  // queries
    const float* Braw = (dir ? src : tgt) + (size_t)b * NPTS * 3;  // targets
    const int colbase = ch * COLSPB;

    // A fragments: 2 row-groups of 32 rows per wave, built once.
    short8 afr[2];
#pragma unroll
    for (int g = 0; g < 2; g++) {
        int row = strip * 256 + g * 128 + w * 32 + l5;
        uint4 w0, w1;
        buildA(Araw[3 * row], Araw[3 * row + 1], Araw[3 * row + 2], w0, w1);
        U4S8 t; t.u = half ? w1 : w0;
        afr[g] = t.s;
    }

    // Pipelined B staging: raw float loads -> regs (early), convert+write (late).
    float nx[2][3];
    auto loadRaw = [&](int c) {
#pragma unroll
        for (int k = 0; k < 2; k++) {
            int p = colbase + c * CHUNKC + (int)threadIdx.x + k * 256;
            nx[k][0] = Braw[3 * p + 0];
            nx[k][1] = Braw[3 * p + 1];
            nx[k][2] = Braw[3 * p + 2];
        }
    };
    auto convertWrite = [&](int bi) {
#pragma unroll
        for (int k = 0; k < 2; k++) {
            int lp = (int)threadIdx.x + k * 256;
            uint4 w0, w1;
            buildB(nx[k][0], nx[k][1], nx[k][2], w0, w1);
            sbuf[bi][0][lp] = w0;
            sbuf[bi][1][lp] = w1;
        }
    };

    const float16 z16 = {0.f,0.f,0.f,0.f,0.f,0.f,0.f,0.f,
                         0.f,0.f,0.f,0.f,0.f,0.f,0.f,0.f};
    float rm[2][16];
#pragma unroll
    for (int g = 0; g < 2; g++)
#pragma unroll
        for (int r = 0; r < 16; r++) rm[g][r] = 1e30f;

    loadRaw(0);
    convertWrite(0);
    for (int c = 0; c < NCHUNKS; c++) {
        __syncthreads();              // buf[c&1] written; prior-iter reads done
        if (c + 1 < NCHUNKS) loadRaw(c + 1);          // issue, don't wait
        const int bi = c & 1;
#pragma unroll 2
        for (int j2 = 0; j2 < CHUNKC / 64; j2++) {    // 8 steps of 64 cols
            U4S8 t0, t1;
            t0.u = sbuf[bi][half][j2 * 64 + l5];
            t1.u = sbuf[bi][half][j2 * 64 + 32 + l5];
#pragma unroll
            for (int g = 0; g < 2; g++) {
                float16 a0 = __builtin_amdgcn_mfma_f32_32x32x16_bf16(afr[g], t0.s, z16, 0, 0, 0);
                float16 a1 = __builtin_amdgcn_mfma_f32_32x32x16_bf16(afr[g], t1.s, z16, 0, 0, 0);
#pragma unroll
                for (int r = 0; r < 16; r++)
                    rm[g][r] = fminf(fminf(a0[r], a1[r]), rm[g][r]);   // v_min3
            }
        }
        if (c + 1 < NCHUNKS) convertWrite((c + 1) & 1);   // vmcnt hidden above
    }

    // Col-fold within half (masks 1..16 over lane&31). Then lanes l5==0 hold
    // final partial mins for rows (r&3)+8*(r>>2)+4*half of each group.
#pragma unroll
    for (int mask = 1; mask <= 16; mask <<= 1)
#pragma unroll
        for (int g = 0; g < 2; g++)
#pragma unroll
            for (int r = 0; r < 16; r++)
                rm[g][r] = fminf(rm[g][r], __shfl_xor(rm[g][r], mask, 64));

    if (l5 == 0) {
        unsigned int* mrow = mins + (size_t)(dir * BATCH + b) * NPTS;
#pragma unroll
        for (int g = 0; g < 2; g++)
#pragma unroll
            for (int r = 0; r < 16; r++) {
                int row = strip * 256 + g * 128 + w * 32 + (r & 3) + 8 * (r >> 2) + 4 * half;
                float v = fmaxf(rm[g][r], 0.0f);
                atomicMin(&mrow[row], __float_as_uint(v));
            }
    }
}

__global__ __launch_bounds__(256) void chamfer_reduce_kernel(
    const unsigned int* __restrict__ mins, float* __restrict__ out)
{
    float s = 0.0f;
    for (int idx = blockIdx.x * blockDim.x + threadIdx.x; idx < NMINS;
         idx += gridDim.x * blockDim.x) {
        s += __uint_as_float(mins[idx]);
    }
#pragma unroll
    for (int off = 32; off > 0; off >>= 1) s += __shfl_down(s, off, 64);
    __shared__ float wsum[4];
    int lane = threadIdx.x & 63;
    int w = threadIdx.x >> 6;
    if (lane == 0) wsum[w] = s;
    __syncthreads();
    if (threadIdx.x == 0) {
        float tot = wsum[0] + wsum[1] + wsum[2] + wsum[3];
        atomicAdd(out, tot * (1.0f / (float)NPTS));
    }
}

extern "C" void kernel_launch(void* const* d_in, const int* in_sizes, int n_in,
                              void* d_out, int out_size, void* d_ws, size_t ws_size,
                              hipStream_t stream)
{
    const float* src = (const float*)d_in[0];
    const float* tgt = (const float*)d_in[1];
    float* out = (float*)d_out;
    unsigned int* mins = (unsigned int*)d_ws;

    hipMemsetAsync(mins, 0xFF, (size_t)NMINS * sizeof(unsigned int), stream);
    hipMemsetAsync(out, 0, sizeof(float), stream);

    chamfer_mfma_kernel<<<2 * BATCH * NSTRIPS * 2, 256, 0, stream>>>(src, tgt, mins);
    chamfer_reduce_kernel<<<128, 256, 0, stream>>>(mins, out);
}